// Round 4
// baseline (2884.639 us; speedup 1.0000x reference)
//
#include <hip/hip_runtime.h>

#define T_LEN   512
#define H_DIM   128
#define OUT_DIM 7
#define TC      16                // timesteps per chunk (prologue N=16 cols = steps)
#define NCHUNK  (T_LEN / TC)      // 32
#define NTHREADS 256              // 4 waves
#define NBLK    512               // 1 batch row per block -> 2 blocks/CU

typedef __bf16 bf16x8 __attribute__((ext_vector_type(8)));
typedef float  f32x4  __attribute__((ext_vector_type(4)));

// Gate-row permutation: MFMA row p <-> original W row orig(p)=128*(p&3)+(p>>2)
// => acc[i][r] = gate r (i,f,g,o) of element j = 4*mt + q,  mt = w + 4i.
__device__ __forceinline__ int orig_row(int p) { return ((p & 3) << 7) | (p >> 2); }

struct __align__(16) SharedMem {
  float  xg[4][TC][33][4];   // [wave][s][slot(32)+1 pad][f32x4]; stride/s=132 words -> conflict-min
  float  gw[4][32][4];       // [wave][slot][f32x4] step handoff (wave-local)
  float  biasc[H_DIM][4];    // [j][gate] b_ih+b_hh
  float  z[H_DIM];           // fc1 out
  __bf16 h[2][H_DIM];        // double-buffered hidden state
  __bf16 hist[TC][H_DIM];    // chunk h history -> batched global store
};

__device__ __forceinline__ float sigf(float x) {
  return __builtin_amdgcn_rcpf(1.f + __expf(-x));
}
__device__ __forceinline__ float tanh_fast(float x) {
  x = fminf(fmaxf(x, -15.f), 15.f);
  float e = __expf(2.f * x);
  return (e - 1.f) * __builtin_amdgcn_rcpf(e + 1.f);
}
__device__ __forceinline__ bf16x8 load8_f32_bf16(const float* p) {
  const f32x4 a = *(const f32x4*)p;
  const f32x4 b = *(const f32x4*)(p + 4);
  bf16x8 r;
  #pragma unroll
  for (int j = 0; j < 4; ++j) { r[j] = (__bf16)a[j]; r[4 + j] = (__bf16)b[j]; }
  return r;
}
__device__ __forceinline__ bf16x8 zero_bf16x8() {
  bf16x8 r;
  #pragma unroll
  for (int j = 0; j < 8; ++j) r[j] = (__bf16)0.f;
  return r;
}

__global__ __launch_bounds__(NTHREADS, 2)   // <=256 VGPR, 2 blocks/CU
void lstm_kernel(const float* __restrict__ x,
                 const float* __restrict__ wih0, const float* __restrict__ whh0,
                 const float* __restrict__ bih0, const float* __restrict__ bhh0,
                 const float* __restrict__ wih1, const float* __restrict__ whh1,
                 const float* __restrict__ bih1, const float* __restrict__ bhh1,
                 const float* __restrict__ wih2, const float* __restrict__ whh2,
                 const float* __restrict__ bih2, const float* __restrict__ bhh2,
                 const float* __restrict__ fc1w, const float* __restrict__ fc1b,
                 const float* __restrict__ fc2w, const float* __restrict__ fc2b,
                 float* __restrict__ out, __bf16* __restrict__ buf)
{
  __shared__ SharedMem sh;
  const int tid = threadIdx.x;
  const int w   = tid >> 6;    // wave 0..3
  const int l   = tid & 63;
  const int q   = l >> 4;
  const int n16 = l & 15;
  const int bg  = blockIdx.x;  // one batch row per block

  // gate-lane mapping (l<32): slot -> (i=slot>>2, q=slot&3), j = 4w+16i+q
  const int gslot = l & 31;
  const int gj    = 4 * w + 16 * (gslot >> 2) + (gslot & 3);

  const float* WIH[3] = {wih0, wih1, wih2};
  const float* WHH[3] = {whh0, whh1, whh2};
  const float* BIH[3] = {bih0, bih1, bih2};
  const float* BHH[3] = {bhh0, bhh1, bhh2};

  for (int lyr = 0; lyr < 3; ++lyr) {
    const float* w_ih = WIH[lyr];
    const float* w_hh = WHH[lyr];
    const int kin_chunks = (lyr == 0) ? 1 : 4;

    // ---- resident W_hh A-frags (permuted rows), converted once per layer ----
    bf16x8 whhf[8][4];   // 128 VGPRs
    #pragma unroll
    for (int i = 0; i < 8; ++i) {
      const int r0 = orig_row(16 * (w + 4 * i) + n16) * H_DIM;
      #pragma unroll
      for (int kc = 0; kc < 4; ++kc)
        whhf[i][kc] = load8_f32_bf16(w_hh + r0 + kc * 32 + q * 8);
    }
    if (tid < H_DIM) {
      #pragma unroll
      for (int r = 0; r < 4; ++r)
        sh.biasc[tid][r] = BIH[lyr][(r << 7) + tid] + BHH[lyr][(r << 7) + tid];
    }
    if (tid < 2 * H_DIM) (&sh.h[0][0])[tid] = (__bf16)0.f;
    float c_st = 0.f;
    __syncthreads();

    bf16x8 pre[4];               // next-prologue B-frags (global prefetch)
    auto load_pre = [&](int c) {
      const int t = c * TC + n16;         // col n16 = step-in-chunk
      if (lyr == 0) {
        pre[0] = zero_bf16x8();
        if (q == 0) pre[0] = load8_f32_bf16(x + ((size_t)bg * T_LEN + t) * 8);
      } else {
        #pragma unroll
        for (int kc = 0; kc < 4; ++kc)
          pre[kc] = *(const bf16x8*)(buf + ((size_t)bg * T_LEN + t) * H_DIM
                                         + kc * 32 + q * 8);
      }
    };
    load_pre(0);

    f32x4 cin[8];                // xg C-init for current step (prefetched)

    for (int c0 = 0; c0 < NCHUNK; ++c0) {
      const int t0 = c0 * TC;

      // ---- prologue: xg for 16 steps; col n16 = step ----
      {
        f32x4 acc[8];
        #pragma unroll
        for (int i = 0; i < 8; ++i)
          acc[i] = *(const f32x4*)&sh.biasc[4 * w + 16 * i + q][0];  // bcast over n16
        for (int kc = 0; kc < kin_chunks; ++kc) {   // wave-uniform
          #pragma unroll
          for (int i = 0; i < 8; ++i) {
            const int p = 16 * (w + 4 * i) + n16;
            bf16x8 wf;
            if (lyr == 0) {
              wf = zero_bf16x8();
              if (q == 0) wf = load8_f32_bf16(w_ih + orig_row(p) * 8);
            } else {
              wf = load8_f32_bf16(w_ih + orig_row(p) * H_DIM + kc * 32 + q * 8);
            }
            acc[i] = __builtin_amdgcn_mfma_f32_16x16x32_bf16(wf, pre[kc], acc[i], 0, 0, 0);
          }
        }
        #pragma unroll
        for (int i = 0; i < 8; ++i) {
          *(f32x4*)&sh.xg[w][n16][4 * i + q][0] = acc[i];  // wave-private
          cin[i] = acc[i];     // col n16 holds step-n16 xg; col 0 (the used one) = s=0
        }
      }
      if (c0 + 1 < NCHUNK) load_pre(c0 + 1);   // lands during the 16 steps
      __syncthreads();                          // also fences prev-chunk hist reads

      // ---- 16 recurrence steps, one block-barrier each ----
      for (int s = 0; s < TC; ++s) {
        const int cur = s & 1, nxt = cur ^ 1;

        f32x4 acc[8];
        #pragma unroll
        for (int i = 0; i < 8; ++i) acc[i] = cin[i];
        #pragma unroll
        for (int kc = 0; kc < 4; ++kc) {
          const bf16x8 bfrag = *(const bf16x8*)&sh.h[cur][kc * 32 + q * 8]; // bcast
          #pragma unroll
          for (int i = 0; i < 8; ++i)
            acc[i] = __builtin_amdgcn_mfma_f32_16x16x32_bf16(whhf[i][kc], bfrag, acc[i], 0, 0, 0);
        }
        if (n16 == 0) {          // col 0 = real batch row: hand off full gates
          #pragma unroll
          for (int i = 0; i < 8; ++i)
            *(f32x4*)&sh.gw[w][4 * i + q][0] = acc[i];
        }
        if (s + 1 < TC) {        // prefetch next step's xg C-init (off critical path)
          #pragma unroll
          for (int i = 0; i < 8; ++i)
            cin[i] = *(const f32x4*)&sh.xg[w][s + 1][4 * i + q][0];
        }
        __builtin_amdgcn_wave_barrier();   // DS pipe is in-order within wave
        if (l < 32) {                      // dense: 1 element per lane
          const f32x4 gv = *(const f32x4*)&sh.gw[w][gslot][0];
          const float gi = gv[0], gf = gv[1], gg = gv[2], go = gv[3];
          c_st = sigf(gf) * c_st + sigf(gi) * tanh_fast(gg);
          const __bf16 hb = (__bf16)(sigf(go) * tanh_fast(c_st));
          sh.h[nxt][gj]  = hb;
          sh.hist[s][gj] = hb;
        }
        __syncthreads();
      }

      // ---- batched hist -> buf (in-place chunk reuse across layers) ----
      if (lyr < 2) {
        const int s2 = tid >> 4, k8 = (tid & 15) * 8;
        const bf16x8 v = *(const bf16x8*)&sh.hist[s2][k8];
        *(bf16x8*)(buf + ((size_t)bg * T_LEN + t0 + s2) * H_DIM + k8) = v;
      }
    }
  }

  // ---- FC head: final h in sh.h[0] (s=15 -> nxt=0) ----
  if (tid < H_DIM) {
    float a = fc1b[tid];
    const float* wr = fc1w + tid * H_DIM;
    #pragma unroll 8
    for (int k = 0; k < H_DIM; ++k)
      a += (float)sh.h[0][k] * wr[k];
    sh.z[tid] = fmaxf(a, 0.f);
  }
  __syncthreads();
  if (tid < OUT_DIM) {
    float a = fc2b[tid];
    for (int k = 0; k < H_DIM; ++k)
      a += sh.z[k] * fc2w[tid * H_DIM + k];
    out[(size_t)bg * OUT_DIM + tid] = a;
  }
}

extern "C" void kernel_launch(void* const* d_in, const int* in_sizes, int n_in,
                              void* d_out, int out_size, void* d_ws, size_t ws_size,
                              hipStream_t stream) {
  const float* x    = (const float*)d_in[0];
  const float* wih0 = (const float*)d_in[1];
  const float* whh0 = (const float*)d_in[2];
  const float* bih0 = (const float*)d_in[3];
  const float* bhh0 = (const float*)d_in[4];
  const float* wih1 = (const float*)d_in[5];
  const float* whh1 = (const float*)d_in[6];
  const float* bih1 = (const float*)d_in[7];
  const float* bhh1 = (const float*)d_in[8];
  const float* wih2 = (const float*)d_in[9];
  const float* whh2 = (const float*)d_in[10];
  const float* bih2 = (const float*)d_in[11];
  const float* bhh2 = (const float*)d_in[12];
  const float* fc1w = (const float*)d_in[13];
  const float* fc1b = (const float*)d_in[14];
  const float* fc2w = (const float*)d_in[15];
  const float* fc2b = (const float*)d_in[16];
  float* out  = (float*)d_out;
  __bf16* buf = (__bf16*)d_ws;   // [512][512][128] bf16 = 64 MiB, block-private rows

  lstm_kernel<<<dim3(NBLK), dim3(NTHREADS), 0, stream>>>(
      x, wih0, whh0, bih0, bhh0, wih1, whh1, bih1, bhh1,
      wih2, whh2, bih2, bhh2, fc1w, fc1b, fc2w, fc2b, out, buf);
}